// Round 1
// baseline (133.207 us; speedup 1.0000x reference)
//
#include <hip/hip_runtime.h>

// ClebschCombiningSingleUnrolled: out[mu] += mult * X1[m1] * X2[m2] (elementwise over N*D)
// M=9 channels, K=100 terms, P = N*D = 1048576 floats per channel.
//
// Strategy: per block, stage a 512-float tile of all 9 channels of X1 and X2
// into LDS (36 KB) via global_load_lds(16B). mu is sorted -> static per-segment
// accumulator (no runtime register indexing). Runtime m1/m2 become LDS byte
// offsets from a packed plan precomputed in d_ws by a tiny prep kernel.

#define M_CH 9
#define TILE 512            // floats per channel per block
#define THREADS 128         // THREADS * 4 == TILE
#define PLAN_PAD 128        // padded plan entries (K=100 -> prefetch k+1 safe)

typedef const void __attribute__((address_space(1))) * gcptr;
typedef void       __attribute__((address_space(3))) * lsptr;

__global__ __launch_bounds__(128) void prep_kernel(
    const int* __restrict__ m1, const int* __restrict__ m2,
    const int* __restrict__ mu, const float* __restrict__ mult,
    int K, int* __restrict__ ws) {
    __shared__ int smu[PLAN_PAD];
    int t = threadIdx.x;
    if (t < K) smu[t] = mu[t];
    __syncthreads();
    int4* plan = (int4*)(ws + 16);
    if (t < K) {
        int4 e;
        e.x = m1[t] * (TILE * 4);              // byte offset of X1 channel row in LDS
        e.y = (M_CH + m2[t]) * (TILE * 4);     // byte offset of X2 channel row in LDS
        e.z = __float_as_int(mult[t]);
        e.w = 0;
        plan[t] = e;
    } else if (t < PLAN_PAD) {
        int4 e; e.x = 0; e.y = M_CH * TILE * 4; e.z = 0; e.w = 0;  // mult=0 pad
        plan[t] = e;
    }
    // segment boundaries: seg[m] = #(mu[k] < m); seg[0]=0, seg[9]=K (mu sorted)
    if (t <= M_CH) {
        int c = 0;
        for (int k = 0; k < K; ++k) c += (smu[k] < t) ? 1 : 0;
        ws[t] = c;
    }
}

__global__ __launch_bounds__(THREADS) void cleb_kernel(
    const float* __restrict__ X1, const float* __restrict__ X2,
    const int* __restrict__ ws, float* __restrict__ out, int P) {
    __shared__ float lds[2 * M_CH * TILE];   // 36 KB
    const int tid = threadIdx.x;
    const int base = blockIdx.x * TILE;

    const float* src1 = X1 + base + tid * 4;
    const float* src2 = X2 + base + tid * 4;
    // stage 9 channels x {X1,X2}: LDS dest = uniform row base + lane*16B (valid pattern)
    #pragma unroll
    for (int m = 0; m < M_CH; ++m) {
        __builtin_amdgcn_global_load_lds((gcptr)(src1 + m * P),
                                         (lsptr)&lds[m * TILE + tid * 4], 16, 0, 0);
        __builtin_amdgcn_global_load_lds((gcptr)(src2 + m * P),
                                         (lsptr)&lds[(M_CH + m) * TILE + tid * 4], 16, 0, 0);
    }

    int seg[M_CH + 1];
    #pragma unroll
    for (int i = 0; i <= M_CH; ++i) seg[i] = ws[i];
    const int4* plan = (const int4*)(ws + 16);

    __syncthreads();   // drains vmcnt -> LDS tiles ready

    const char* ldsb = (const char*)lds;
    const int lane_off = tid * 16;
    float* outp = out + base + tid * 4;

    #pragma unroll
    for (int m = 0; m < M_CH; ++m) {
        float4 acc = make_float4(0.f, 0.f, 0.f, 0.f);
        const int s = seg[m], e = seg[m + 1];
        int4 pe = plan[s];                    // safe: plan padded
        #pragma unroll 2
        for (int k = s; k < e; ++k) {
            int4 pn = plan[k + 1];            // prefetch next entry (padded)
            const float4 a = *(const float4*)(ldsb + pe.x + lane_off);
            const float4 b = *(const float4*)(ldsb + pe.y + lane_off);
            const float c = __int_as_float(pe.z);
            acc.x = fmaf(c * a.x, b.x, acc.x);
            acc.y = fmaf(c * a.y, b.y, acc.y);
            acc.z = fmaf(c * a.z, b.z, acc.z);
            acc.w = fmaf(c * a.w, b.w, acc.w);
            pe = pn;
        }
        *(float4*)(outp + m * P) = acc;       // coalesced 16B store
    }
}

extern "C" void kernel_launch(void* const* d_in, const int* in_sizes, int n_in,
                              void* d_out, int out_size, void* d_ws, size_t ws_size,
                              hipStream_t stream) {
    const float* X1   = (const float*)d_in[0];
    const float* X2   = (const float*)d_in[1];
    const int*   m1   = (const int*)d_in[2];
    const int*   m2   = (const int*)d_in[3];
    const int*   mu   = (const int*)d_in[4];
    const float* mult = (const float*)d_in[5];
    float* out = (float*)d_out;
    int*   ws  = (int*)d_ws;

    const int K = in_sizes[2];                 // 100
    const int P = in_sizes[0] / M_CH;          // 1048576

    prep_kernel<<<1, 128, 0, stream>>>(m1, m2, mu, mult, K, ws);
    cleb_kernel<<<P / TILE, THREADS, 0, stream>>>(X1, X2, ws, out, P);
}